// Round 6
// baseline (39.480 us; speedup 1.0000x reference)
//
#include <hip/hip_runtime.h>
#include <hip/hip_bf16.h>

#define NV 16384
#define NT 256
#define NTILES 512                  // 32-point MFMA tiles per mesh
#define RT_CHUNK 64                 // ref tiles per nn block
#define NCHUNK (NTILES / RT_CHUNK)  // 8 chunks per direction
#define STG 32                      // tiles staged in LDS per round (32 KB)
#define QT_PER_BLOCK 8              // 4 waves x 2 qtiles
#define NN_BX (NTILES / QT_PER_BLOCK)  // 64
#define RES_QPW 4                   // queries per wave (resolve)
#define RES_QPB (4 * RES_QPW)       // 16 per block
#define RES_BLOCKS (NV / RES_QPB)   // 1024 per direction
#define NPART (2 * RES_BLOCKS)      // 2048 partials

typedef __attribute__((ext_vector_type(8))) short bf16x8;
typedef __attribute__((ext_vector_type(16))) float f32x16;

__device__ __forceinline__ short bf16bits(float f) {
    __hip_bfloat16 h = __float2bfloat16(f);
    return *reinterpret_cast<short*>(&h);
}
__device__ __forceinline__ float bf16tof(short s) {
    __hip_bfloat16 h = *reinterpret_cast<__hip_bfloat16*>(&s);
    return __bfloat162float(h);
}
__device__ __forceinline__ unsigned sortable(float f) {
    unsigned u = __float_as_uint(f);
    return (u & 0x80000000u) ? ~u : (u | 0x80000000u);
}
__device__ __forceinline__ float min3f(float a, float b, float c) {
    float r;
    asm("v_min3_f32 %0, %1, %2, %3" : "=v"(r) : "v"(a), "v"(b), "v"(c));
    return r;
}
// min over the 16 f32 of one MFMA accumulator (in-lane), 8 ops, depth 3
__device__ __forceinline__ float tree16(const f32x16& c) {
    float t0 = min3f(c[0], c[1], c[2]);
    float t1 = min3f(c[3], c[4], c[5]);
    float t2 = min3f(c[6], c[7], c[8]);
    float t3 = min3f(c[9], c[10], c[11]);
    float t4 = min3f(c[12], c[13], c[14]);
    float s0 = min3f(t0, t1, c[15]);
    float s1 = min3f(t2, t3, t4);
    return fminf(s0, s1);
}

// Fragment packing (K=11 of 16). Metric m(ref,query) = 0.5*||r||^2 - q.r:
//   A(ref) k:   [rh.x rh.y rh.z | rl.x rl.y rl.z | rh.x rh.y || rh.z nh nl | 0..]
//   B(query) k: [-qh.x -qh.y -qh.z | -qh.x -qh.y -qh.z | -ql.x -ql.y || -ql.z 1 1 | 0..]
// vh = bf16(v), vl = bf16(v - f32(vh)), n = 0.5||r||^2 split nh+nl.
// A and B use the same (half,elem)->k mapping so any permutation cancels.
__device__ __forceinline__ bf16x8 make_a(float x, float y, float z, int half) {
    short hx = bf16bits(x), hy = bf16bits(y), hz = bf16bits(z);
    short lx = bf16bits(x - bf16tof(hx));
    short ly = bf16bits(y - bf16tof(hy));
    short lz = bf16bits(z - bf16tof(hz));
    float n  = 0.5f * fmaf(z, z, fmaf(y, y, x * x));
    short nh = bf16bits(n);
    short nl = bf16bits(n - bf16tof(nh));
    bf16x8 v;
    v[0] = half ? hz : hx;  v[1] = half ? nh : hy;
    v[2] = half ? nl : hz;  v[3] = half ? (short)0 : lx;
    v[4] = half ? (short)0 : ly;  v[5] = half ? (short)0 : lz;
    v[6] = half ? (short)0 : hx;  v[7] = half ? (short)0 : hy;
    return v;
}
__device__ __forceinline__ bf16x8 make_b(float x, float y, float z, int half) {
    short hx = bf16bits(x), hy = bf16bits(y), hz = bf16bits(z);
    short nhx = bf16bits(-x), nhy = bf16bits(-y), nhz = bf16bits(-z);
    short nlx = bf16bits(bf16tof(hx) - x);
    short nly = bf16bits(bf16tof(hy) - y);
    short nlz = bf16bits(bf16tof(hz) - z);
    const short one = 0x3F80;
    bf16x8 v;
    v[0] = half ? nlz : nhx;  v[1] = half ? one : nhy;
    v[2] = half ? one : nhz;  v[3] = half ? (short)0 : nhx;
    v[4] = half ? (short)0 : nhy;  v[5] = half ? (short)0 : nhz;
    v[6] = half ? (short)0 : nlx;  v[7] = half ? (short)0 : nly;
    return v;
}

// Pack all A (ref-side) fragments ONCE (R5 repacked them 64x redundantly in
// every nn block). 65536 slots, 16 B each -> 1 MB, L2-resident.
__global__ __launch_bounds__(NT) void prep_kernel(
    const float* __restrict__ pred_v, const float* __restrict__ trg_v,
    short* __restrict__ Apack)
{
    int gid = blockIdx.x * NT + threadIdx.x;  // 0..65535
    int d   = gid >> 15;                      // direction
    int rem = gid & 32767;
    int t   = rem >> 6;
    int l   = rem & 63;
    const float* rpts = d ? trg_v : pred_v;   // refs for dir d
    int p = t * 32 + (l & 31);
    bf16x8 v = make_a(rpts[3 * p + 0], rpts[3 * p + 1], rpts[3 * p + 2], l >> 5);
    *(bf16x8*)(Apack + ((size_t)gid) * 8) = v;
}

// Pass 1: MFMA all-pairs min. Block: 4 waves x 2 qtiles, one 64-rtile chunk,
// one direction. A fragments copied (coalesced 16 B/lane) from Apack into
// LDS; B fragments packed in registers (2 make_b per wave). Per rtile-pair:
// 4 MFMAs + min3 trees; track (dmin, pairid); merge lane halves; store
// per-chunk key (no atomics).
__global__ __launch_bounds__(NT, 4) void nn_mfma_kernel(
    const float* __restrict__ pred_v, const float* __restrict__ trg_v,
    const short* __restrict__ Apack, unsigned long long* __restrict__ results)
{
    __shared__ short lds[STG * 512];   // 32 KB
    const int tid = threadIdx.x, lane = tid & 63, w = tid >> 6;
    const int dir = blockIdx.z;
    const float* qpts = dir ? pred_v : trg_v;
    const int qt0 = blockIdx.x * QT_PER_BLOCK + w * 2;
    const int rtb = blockIdx.y * RT_CHUNK;
    const int half = lane >> 5;
    const size_t dbase = (size_t)dir * NTILES * 512;

    const int qp0 = qt0 * 32 + (lane & 31);
    bf16x8 b0 = make_b(qpts[3 * qp0 + 0], qpts[3 * qp0 + 1], qpts[3 * qp0 + 2], half);
    bf16x8 b1 = make_b(qpts[3 * (qp0 + 32) + 0], qpts[3 * (qp0 + 32) + 1],
                       qpts[3 * (qp0 + 32) + 2], half);

    float dmin0 = 1e30f, dmin1 = 1e30f;
    int bp0 = 0, bp1 = 0;
    const f32x16 zc = {};

    for (int g = 0; g < RT_CHUNK / STG; g++) {
        __syncthreads();
        // Coalesced copy: source slots contiguous, 16 B per thread-iter.
        const bf16x8* src = (const bf16x8*)(Apack + dbase + (size_t)(rtb + g * STG) * 512);
#pragma unroll
        for (int s = 0; s < (STG * 64) / NT; s++) {
            int slot = s * NT + tid;
            *(bf16x8*)(&lds[slot * 8]) = src[slot];
        }
        __syncthreads();
#pragma unroll 2
        for (int p = 0; p < STG / 2; p++) {
            bf16x8 a0 = *(const bf16x8*)(&lds[(2 * p) * 512 + lane * 8]);
            f32x16 c0 = __builtin_amdgcn_mfma_f32_32x32x16_bf16(a0, b0, zc, 0, 0, 0);
            f32x16 c1 = __builtin_amdgcn_mfma_f32_32x32x16_bf16(a0, b1, zc, 0, 0, 0);
            float u0 = tree16(c0), u1 = tree16(c1);
            bf16x8 a1 = *(const bf16x8*)(&lds[(2 * p + 1) * 512 + lane * 8]);
            f32x16 d0 = __builtin_amdgcn_mfma_f32_32x32x16_bf16(a1, b0, zc, 0, 0, 0);
            f32x16 d1 = __builtin_amdgcn_mfma_f32_32x32x16_bf16(a1, b1, zc, 0, 0, 0);
            float m0 = fminf(u0, tree16(d0));
            float m1 = fminf(u1, tree16(d1));
            int pid = blockIdx.y * (RT_CHUNK / 2) + g * (STG / 2) + p;
            bool lt0 = m0 < dmin0; dmin0 = lt0 ? m0 : dmin0; bp0 = lt0 ? pid : bp0;
            bool lt1 = m1 < dmin1; dmin1 = lt1 ? m1 : dmin1; bp1 = lt1 ? pid : bp1;
        }
    }

    unsigned long long k0 = ((unsigned long long)sortable(dmin0) << 32) | (unsigned)bp0;
    unsigned long long k1 = ((unsigned long long)sortable(dmin1) << 32) | (unsigned)bp1;
    unsigned long long o0 = __shfl_xor(k0, 32); k0 = (o0 < k0) ? o0 : k0;
    unsigned long long o1 = __shfl_xor(k1, 32); k1 = (o1 < k1) ? o1 : k1;
    if (lane < 32) {
        size_t base = ((size_t)dir * NCHUNK + blockIdx.y) * NV;
        results[base + qt0 * 32 + lane] = k0;
        results[base + (qt0 + 1) * 32 + lane] = k1;
    }
}

// Pass 2 + loss: 4 queries per wave (sequential, for ILP). Per query: min
// over 8 chunk keys (lowest pairid wins ties), exact fp32 rescan of the
// winning 64-ref pair (strict < per lane, packed-u64 lane-min -> first-
// occurrence argmin), lane 0 accumulates MSE; deterministic block reduce.
__global__ __launch_bounds__(NT) void resolve_loss_kernel(
    const float* __restrict__ pred_v, const float* __restrict__ trg_v,
    const float* __restrict__ pred_e, const float* __restrict__ trg_e,
    const unsigned long long* __restrict__ results, float* __restrict__ partials)
{
    const int dir = blockIdx.y;
    const float* qpts = dir ? pred_v : trg_v;
    const float* rpts = dir ? trg_v : pred_v;
    const float* qe_b = dir ? pred_e : trg_e;
    const float* re_b = dir ? trg_e : pred_e;

    const int tid = threadIdx.x, lane = tid & 63, wv = tid >> 6;
    float acc = 0.0f;

    for (int qq = 0; qq < RES_QPW; qq++) {
        const int q = blockIdx.x * RES_QPB + wv * RES_QPW + qq;

        unsigned long long key = 0xFFFFFFFFFFFFFFFFULL;
        if (lane < NCHUNK)
            key = results[((size_t)dir * NCHUNK + lane) * NV + q];
        unsigned long long o;
        o = __shfl_xor(key, 4); key = (o < key) ? o : key;
        o = __shfl_xor(key, 2); key = (o < key) ? o : key;
        o = __shfl_xor(key, 1); key = (o < key) ? o : key;
        key = __shfl(key, 0);
        const int pair = (int)(unsigned)(key & 0xFFFFFFFFULL);
        const int i = pair * 64 + lane;

        float nqx = -qpts[3 * q + 0], nqy = -qpts[3 * q + 1], nqz = -qpts[3 * q + 2];
        float x = rpts[3 * i + 0], y = rpts[3 * i + 1], z = rpts[3 * i + 2];
        float rw = 0.5f * fmaf(z, z, fmaf(y, y, x * x));
        float s = fmaf(nqx, x, rw);
        s = fmaf(nqy, y, s);
        s = fmaf(nqz, z, s);

        unsigned long long kk = ((unsigned long long)sortable(s) << 32) | (unsigned)i;
#pragma unroll
        for (int off = 32; off > 0; off >>= 1) {
            unsigned long long t = __shfl_xor(kk, off);
            kk = (t < kk) ? t : kk;
        }
        if (lane == 0) {
            int j = (int)(unsigned)(kk & 0xFFFFFFFFULL);
            float dx = qe_b[3 * q + 0] - re_b[3 * j + 0];
            float dy = qe_b[3 * q + 1] - re_b[3 * j + 1];
            float dz = qe_b[3 * q + 2] - re_b[3 * j + 2];
            acc += fmaf(dx, dx, fmaf(dy, dy, dz * dz));
        }
    }

    __shared__ float wsum[4];
    if (lane == 0) wsum[wv] = acc;
    __syncthreads();
    if (tid == 0)
        partials[dir * RES_BLOCKS + blockIdx.x] =
            (wsum[0] + wsum[1]) + (wsum[2] + wsum[3]);
}

__global__ __launch_bounds__(NT) void final_kernel(
    const float* __restrict__ partials, float* __restrict__ out)
{
    const int tid = threadIdx.x;
    float acc = 0.0f;
#pragma unroll
    for (int t = 0; t < NPART / NT; t++) acc += partials[t * NT + tid];
    __shared__ float red[NT];
    red[tid] = acc;
    __syncthreads();
    for (int s = NT / 2; s > 0; s >>= 1) {
        if (tid < s) red[tid] += red[tid + s];
        __syncthreads();
    }
    if (tid == 0) out[0] = red[0] * (1.0f / 49152.0f);  // both losses: mean over V*3
}

extern "C" void kernel_launch(void* const* d_in, const int* in_sizes, int n_in,
                              void* d_out, int out_size, void* d_ws, size_t ws_size,
                              hipStream_t stream) {
    const float* pred_v = (const float*)d_in[0];
    const float* trg_v  = (const float*)d_in[1];
    const float* pred_e = (const float*)d_in[2];
    const float* trg_e  = (const float*)d_in[3];
    float* out = (float*)d_out;

    unsigned long long* results = (unsigned long long*)d_ws;  // 2*8*NV u64 = 2 MB
    short* Apack = (short*)(results + 2 * NCHUNK * NV);       // 1 MB
    float* partials = (float*)(Apack + 2 * NTILES * 512);     // 8 KB

    prep_kernel<<<(2 * NTILES * 64) / NT, NT, 0, stream>>>(pred_v, trg_v, Apack);

    nn_mfma_kernel<<<dim3(NN_BX, NCHUNK, 2), NT, 0, stream>>>(
        pred_v, trg_v, Apack, results);

    resolve_loss_kernel<<<dim3(RES_BLOCKS, 2), NT, 0, stream>>>(
        pred_v, trg_v, pred_e, trg_e, results, partials);

    final_kernel<<<1, NT, 0, stream>>>(partials, out);
}